// Round 21
// baseline (374.211 us; speedup 1.0000x reference)
//
#include <hip/hip_runtime.h>
#include <hip/hip_bf16.h>

#define VV 100000
#define EE 50
#define HH 64
#define BB 1024
#define TT 200
// 3H = 192

typedef float v4f __attribute__((ext_vector_type(4)));
typedef float f32x4 __attribute__((ext_vector_type(4)));
typedef _Float16 f16x8 __attribute__((ext_vector_type(8)));
typedef _Float16 f16x2 __attribute__((ext_vector_type(2)));

__device__ __forceinline__ float fsig(float x) {
    return 1.f / (1.f + __expf(-x));
}
__device__ __forceinline__ float ftanh(float x) {
    float e = __expf(2.f * x);
    return 1.f - 2.f / (e + 1.f);
}

// ---------------- Kernel A: embW[v] = emb[v]@Wx + bi (+br for z,r); row-0 pad-mask folded ----
__global__ __launch_bounds__(256) void embw_kernel(
    const float* __restrict__ emb,
    const float* __restrict__ Wx_f, const float* __restrict__ bi_f, const float* __restrict__ br_f,
    const float* __restrict__ Wx_b, const float* __restrict__ bi_b, const float* __restrict__ br_b,
    float* __restrict__ embW_f, float* __restrict__ embW_b)
{
    const float* Wx = blockIdx.y ? Wx_b : Wx_f;
    const float* bi = blockIdx.y ? bi_b : bi_f;
    const float* br = blockIdx.y ? br_b : br_f;
    float* embW     = blockIdx.y ? embW_b : embW_f;
    __shared__ float wx_lds[EE * 192];
    __shared__ float emb_lds[32 * EE];
    const int tid = threadIdx.x;
    const int v0 = blockIdx.x * 32;
    for (int i = tid; i < EE * 192; i += 256) wx_lds[i] = Wx[i];
    for (int i = tid; i < 32 * EE; i += 256) emb_lds[i] = emb[(size_t)v0 * EE + i];
    __syncthreads();
    const int cg = tid & 63;
    const int rg = tid >> 6;
    float acc[8][3];
    #pragma unroll
    for (int i = 0; i < 8; i++) {
        acc[i][0] = bi[cg] + br[cg];              // z: fold br
        acc[i][1] = bi[cg + 64] + br[cg + 64];    // r: fold br
        acc[i][2] = bi[cg + 128];                 // n: br_n stays in the step
    }
    for (int k = 0; k < EE; k++) {
        const float wx0 = wx_lds[k * 192 + cg];
        const float wx1 = wx_lds[k * 192 + cg + 64];
        const float wx2 = wx_lds[k * 192 + cg + 128];
        #pragma unroll
        for (int i = 0; i < 8; i++) {
            const float ev = emb_lds[(rg * 8 + i) * EE + k];
            acc[i][0] = fmaf(ev, wx0, acc[i][0]);
            acc[i][1] = fmaf(ev, wx1, acc[i][1]);
            acc[i][2] = fmaf(ev, wx2, acc[i][2]);
        }
    }
    #pragma unroll
    for (int i = 0; i < 8; i++) {
        const int vrow = v0 + rg * 8 + i;
        const size_t row = (size_t)vrow * 192;
        const bool pad = (vrow == 0);
        embW[row + cg]       = pad ? 38.f : acc[i][0];
        embW[row + cg + 64]  = pad ? 0.f  : acc[i][1];
        embW[row + cg + 128] = pad ? 0.f  : acc[i][2];
    }
}

// ---------------- Kernel B v17: gru14 schedule at 4 seqs/block (2 blocks/CU co-residency) ----
// 512 blocks -> 2 blocks/CU -> 2 co-resident waves/SIMD: two independent 200-step chains
// interleave and hide each other's latencies (the gru4-vs-gru6 measured mechanism).
// Each lane prefetches ONE row's gx (r = lhi, 3 dword loads); consumers obtain the 4 rows
// via 12 intra-wave shuffles (exact). Gates/stores on lhi==0 lanes (C/D rows 0-3).
__global__ __launch_bounds__(256, 1) void gru17_kernel(
    const int* __restrict__ ids,
    const float* __restrict__ eW_f, const float* __restrict__ eW_b,
    const float* __restrict__ Wh_f, const float* __restrict__ br_f,
    const float* __restrict__ Wh_b, const float* __restrict__ br_b,
    _Float16* __restrict__ outb,  // [B, T, 128] f16
    float* __restrict__ hf_out)   // [B, 64] fp32
{
    const int tid  = threadIdx.x;
    const int w    = tid >> 6;
    const int lane = tid & 63;
    const int l15  = lane & 15;
    const int lhi  = lane >> 4;
    const int dir  = blockIdx.y;
    const int b0   = blockIdx.x * 4;
    const float* eW = dir ? eW_b : eW_f;
    const float* Wh = dir ? Wh_b : Wh_f;
    const float* br = dir ? br_b : br_f;
    const int c = 16 * w + l15;   // hidden column 0..63 owned by this lane

    // B-fragments: gate g (0=z,1=r,2=n), k-tile kt; k = 32*kt + 8*lhi + jj, col = 64*g + c.
    f16x8 bw[3][2];
    #pragma unroll
    for (int g = 0; g < 3; g++) {
        #pragma unroll
        for (int kt = 0; kt < 2; kt++) {
            #pragma unroll
            for (int jj = 0; jj < 8; jj++)
                bw[g][kt][jj] = (_Float16)Wh[(size_t)(32 * kt + 8 * lhi + jj) * 192 + 64 * g + c];
        }
    }
    const float brn = br[128 + c];

    __shared__ __align__(16) _Float16 hlds[2][16][88];  // stride 176B; rows 4-15 stay zero
    __shared__ int idsT[TT * 4];                        // transposed [t][seq]
    for (int i = tid; i < TT * 4; i += 256)
        idsT[i] = ids[(size_t)(b0 + (i & 3)) * TT + (i >> 2)];
    for (int i = tid; i < 2 * 16 * 88; i += 256) ((_Float16*)hlds)[i] = (_Float16)0.f;
    float hold[4] = {0.f, 0.f, 0.f, 0.f};   // valid on lhi==0 lanes: h[r][c]
    __syncthreads();

    const int t0 = dir ? (TT - 1) : 0;
    const int dt = dir ? -1 : 1;

    float gxA[3], gxB[3], gxC[3], gxD[3];   // one row (r = lhi) x 3 gates per lane

#define PREF(BANK, SF) { \
    const int tf_ = t0 + (SF) * dt; \
    const int idq_ = idsT[tf_ * 4 + lhi]; \
    const float* p_ = eW + (size_t)idq_ * 192 + c; \
    BANK[0] = p_[0]; BANK[1] = p_[64]; BANK[2] = p_[128]; }

#define STEP(BANK, SCUR) { \
    const int t_ = t0 + (SCUR) * dt; \
    const int nxt_ = cur ^ 1; \
    /* redistribute gx: row r lives on lane 16*r + l15 (same wave, same col) */ \
    float gz_[4], gr_[4], gn_[4]; \
    _Pragma("unroll") \
    for (int r = 0; r < 4; r++) { \
        gz_[r] = __shfl(BANK[0], 16 * r + l15); \
        gr_[r] = __shfl(BANK[1], 16 * r + l15); \
        gn_[r] = __shfl(BANK[2], 16 * r + l15); \
    } \
    const f16x8 a0_ = *(const f16x8*)&hlds[cur][l15][8 * lhi]; \
    const f16x8 a1_ = *(const f16x8*)&hlds[cur][l15][32 + 8 * lhi]; \
    f32x4 az0 = {0.f,0.f,0.f,0.f}, ar0 = {0.f,0.f,0.f,0.f}, an0 = {0.f,0.f,0.f,0.f}; \
    f32x4 az1 = {0.f,0.f,0.f,0.f}, ar1 = {0.f,0.f,0.f,0.f}, an1 = {0.f,0.f,0.f,0.f}; \
    az0 = __builtin_amdgcn_mfma_f32_16x16x32_f16(a0_, bw[0][0], az0, 0, 0, 0); \
    ar0 = __builtin_amdgcn_mfma_f32_16x16x32_f16(a0_, bw[1][0], ar0, 0, 0, 0); \
    an0 = __builtin_amdgcn_mfma_f32_16x16x32_f16(a0_, bw[2][0], an0, 0, 0, 0); \
    az1 = __builtin_amdgcn_mfma_f32_16x16x32_f16(a1_, bw[0][1], az1, 0, 0, 0); \
    ar1 = __builtin_amdgcn_mfma_f32_16x16x32_f16(a1_, bw[1][1], ar1, 0, 0, 0); \
    an1 = __builtin_amdgcn_mfma_f32_16x16x32_f16(a1_, bw[2][1], an1, 0, 0, 0); \
    _Pragma("unroll") \
    for (int r = 0; r < 4; r++) { \
        const float z_  = fsig(gz_[r] + (az0[r] + az1[r])); \
        const float rg2_ = fsig(gr_[r] + (ar0[r] + ar1[r])); \
        const float hh_ = ftanh(gn_[r] + rg2_ * (an0[r] + an1[r] + brn)); \
        const float hn_ = hh_ + z_ * (hold[r] - hh_); \
        hold[r] = hn_; \
    } \
    if (lhi == 0) { \
        _Pragma("unroll") \
        for (int r = 0; r < 4; r++) { \
            hlds[nxt_][r][c] = (_Float16)hold[r]; \
            outb[((size_t)(b0 + r) * TT + t_) * 128 + dir * 64 + c] = (_Float16)hold[r]; \
        } \
    } \
    cur = nxt_; \
    if ((SCUR) + 4 < TT) PREF(BANK, (SCUR) + 4) \
    asm volatile("s_waitcnt lgkmcnt(0)\n\ts_barrier" ::: "memory"); \
    __builtin_amdgcn_sched_barrier(0); }

    PREF(gxA, 0)
    PREF(gxB, 1)
    PREF(gxC, 2)
    PREF(gxD, 3)
    int cur = 0;
    for (int s = 0; s < TT; s += 4) {
        STEP(gxA, s)
        STEP(gxB, s + 1)
        STEP(gxC, s + 2)
        STEP(gxD, s + 3)
    }
#undef PREF
#undef STEP
    if (dir == 0 && lhi == 0) {
        #pragma unroll
        for (int r = 0; r < 4; r++)
            hf_out[(size_t)(b0 + r) * 64 + c] = hold[r];
    }
}

// ---------------- Kernel C: MFMA keys GEMM on f16 outb; f16x2 vectorized context (attn9) ----
#define NTILE 13   // ceil(200/16)

__global__ __launch_bounds__(256) void attn9_kernel(
    const int* __restrict__ ids,
    const _Float16* __restrict__ outb,   // [B,T,128] f16
    const float* __restrict__ hf,        // [B,64] fp32
    const float* __restrict__ Wk, const float* __restrict__ bk,
    const float* __restrict__ Wq, const float* __restrict__ bq,
    const float* __restrict__ We, const float* __restrict__ be,
    float* __restrict__ ctx)             // [B,128]
{
    __shared__ __align__(16) _Float16 wk_sw[1024 * 8];
    __shared__ float q_lds[64];
    __shared__ float we_lds[64];
    __shared__ float e_lds[TT];
    __shared__ float part[4][128];
    const int b = blockIdx.x;
    const int tid = threadIdx.x;
    const int w = tid >> 6;
    const int lane = tid & 63;
    const int l15 = lane & 15;
    const int lhi = lane >> 4;

    #pragma unroll
    for (int i = 0; i < 4; i++) {
        const int slot = tid + 256 * i;
        const int s_l15 = slot & 15;
        const int s_nt  = (slot >> 4) & 3;
        const int s_lhi = (slot >> 6) & 3;
        const int s_ks  = slot >> 8;
        const int kbase = 32 * s_ks + 8 * s_lhi;
        const int col   = 16 * s_nt + s_l15;
        f16x8 v;
        #pragma unroll
        for (int jj = 0; jj < 8; jj++) v[jj] = (_Float16)Wk[(size_t)(kbase + jj) * 64 + col];
        *(f16x8*)&wk_sw[slot * 8] = v;
    }
    if (tid < 64) {
        float qc = bq[tid];
        const float* hfb = hf + (size_t)b * 64;
        for (int k = 0; k < 64; k++) qc = fmaf(hfb[k], Wq[k * 64 + tid], qc);
        q_lds[tid] = qc;
        we_lds[tid] = We[tid];
    }
    __syncthreads();

    for (int tile = w; tile < NTILE; tile += 4) {
        const int t0 = tile * 16;
        const int t = t0 + l15;
        f32x4 acc[4];
        #pragma unroll
        for (int nt = 0; nt < 4; nt++) { acc[nt][0] = 0.f; acc[nt][1] = 0.f; acc[nt][2] = 0.f; acc[nt][3] = 0.f; }
        #pragma unroll
        for (int ks = 0; ks < 4; ks++) {
            f16x8 a;
            if (t < TT) {
                a = *(const f16x8*)(outb + ((size_t)b * TT + t) * 128 + 32 * ks + 8 * lhi);
            } else {
                #pragma unroll
                for (int jj = 0; jj < 8; jj++) a[jj] = (_Float16)0.f;
            }
            #pragma unroll
            for (int nt = 0; nt < 4; nt++) {
                const f16x8 bf = *(const f16x8*)&wk_sw[(ks * 256 + lhi * 64 + nt * 16 + l15) * 8];
                acc[nt] = __builtin_amdgcn_mfma_f32_16x16x32_f16(a, bf, acc[nt], 0, 0, 0);
            }
        }
        float ep0 = 0.f, ep1 = 0.f, ep2 = 0.f, ep3 = 0.f;
        #pragma unroll
        for (int nt = 0; nt < 4; nt++) {
            const int c = 16 * nt + l15;
            const float qn = q_lds[c];
            const float wen = we_lds[c];
            ep0 = fmaf(wen, ftanh(acc[nt][0] + qn), ep0);
            ep1 = fmaf(wen, ftanh(acc[nt][1] + qn), ep1);
            ep2 = fmaf(wen, ftanh(acc[nt][2] + qn), ep2);
            ep3 = fmaf(wen, ftanh(acc[nt][3] + qn), ep3);
        }
        #pragma unroll
        for (int off = 1; off < 16; off <<= 1) {
            ep0 += __shfl_xor(ep0, off);
            ep1 += __shfl_xor(ep1, off);
            ep2 += __shfl_xor(ep2, off);
            ep3 += __shfl_xor(ep3, off);
        }
        if (l15 == 0) {
            const int rbase = t0 + 4 * lhi;
            if (rbase + 0 < TT) e_lds[rbase + 0] = ep0;
            if (rbase + 1 < TT) e_lds[rbase + 1] = ep1;
            if (rbase + 2 < TT) e_lds[rbase + 2] = ep2;
            if (rbase + 3 < TT) e_lds[rbase + 3] = ep3;
        }
    }
    __syncthreads();
    if (w == 0) {
        const float bev = be[0];
        for (int t = lane; t < TT; t += 64) {
            float e = e_lds[t] + bev;
            if (ids[(size_t)b * TT + t] == 0) e -= 1e9f;
            e_lds[t] = e;
        }
        float m = -1e30f;
        for (int t = lane; t < TT; t += 64) m = fmaxf(m, e_lds[t]);
        #pragma unroll
        for (int off = 32; off > 0; off >>= 1) m = fmaxf(m, __shfl_xor(m, off));
        float ssum = 0.f;
        for (int t = lane; t < TT; t += 64) { const float v = __expf(e_lds[t] - m); e_lds[t] = v; ssum += v; }
        #pragma unroll
        for (int off = 32; off > 0; off >>= 1) ssum += __shfl_xor(ssum, off);
        const float inv = 1.f / ssum;
        for (int t = lane; t < TT; t += 64) e_lds[t] *= inv;
    }
    __syncthreads();
    float c0 = 0.f, c1 = 0.f;
    for (int t = w; t < TT; t += 4) {
        const f16x2 hv = *(const f16x2*)(outb + ((size_t)b * TT + t) * 128 + 2 * lane);
        const float wt = e_lds[t];
        c0 = fmaf(wt, (float)hv[0], c0);
        c1 = fmaf(wt, (float)hv[1], c1);
    }
    part[w][2 * lane]     = c0;
    part[w][2 * lane + 1] = c1;
    __syncthreads();
    if (tid < 128)
        ctx[(size_t)b * 128 + tid] = part[0][tid] + part[1][tid] + part[2][tid] + part[3][tid];
}

// ---------------- (fallback, fp32 end-to-end) ----------------
template<bool USE_EMBW>
__global__ __launch_bounds__(192, 2) void gru_kernel(
    const int* __restrict__ ids,
    const float* __restrict__ embW_f, const float* __restrict__ embW_b,
    const float* __restrict__ emb,
    const float* __restrict__ Wx_f, const float* __restrict__ bi_f,
    const float* __restrict__ Wx_b, const float* __restrict__ bi_b,
    const float* __restrict__ Wh_f, const float* __restrict__ br_f,
    const float* __restrict__ Wh_b, const float* __restrict__ br_b,
    float* __restrict__ outb, float* __restrict__ hf_out)
{
    constexpr int R = 4;
    __shared__ float h_lds[R][64];
    __shared__ float rg_lds[R][64];
    __shared__ float hh_lds[R][64];
    __shared__ int ids_lds[R * TT];
    const int tid = threadIdx.x;
    const int w = tid >> 6;
    const int j = tid & 63;
    const int dir = blockIdx.y;
    const int b0 = blockIdx.x * R;
    const float* Wh   = dir ? Wh_b : Wh_f;
    const float* br   = dir ? br_b : br_f;
    const float* Wx   = dir ? Wx_b : Wx_f;
    const float* bi   = dir ? bi_b : bi_f;
    const int c = w * 64 + j;

    float whc[64];
    #pragma unroll
    for (int k = 0; k < 64; k++) whc[k] = Wh[k * 192 + c];
    const float brc = br[c];
    float wxc[EE];
    float bic = 0.f;
    if (!USE_EMBW) {
        #pragma unroll
        for (int k = 0; k < EE; k++) wxc[k] = Wx[k * 192 + c];
        bic = bi[c];
    }
    for (int i = tid; i < R * TT; i += 192) ids_lds[i] = ids[(size_t)b0 * TT + i];
    if (w == 0) {
        #pragma unroll
        for (int r = 0; r < R; r++) h_lds[r][j] = 0.f;
    }
    __syncthreads();

    for (int s = 0; s < TT; s++) {
        const int t = dir ? (TT - 1 - s) : s;
        int idv[R];
        float gxv[R], accv[R];
        #pragma unroll
        for (int r = 0; r < R; r++) idv[r] = ids_lds[r * TT + t];
        #pragma unroll
        for (int r = 0; r < R; r++) {
            float acc = bic;
            const float* er = emb + (size_t)idv[r] * EE;
            #pragma unroll
            for (int k = 0; k < EE; k++) acc = fmaf(er[k], wxc[k], acc);
            gxv[r] = acc;
        }
        #pragma unroll
        for (int r = 0; r < R; r++) {
            float acc = brc;
            const float4* h4 = (const float4*)(&h_lds[r][0]);
            #pragma unroll
            for (int k4 = 0; k4 < 16; k4++) {
                const float4 hv = h4[k4];
                acc = fmaf(hv.x, whc[4 * k4 + 0], acc);
                acc = fmaf(hv.y, whc[4 * k4 + 1], acc);
                acc = fmaf(hv.z, whc[4 * k4 + 2], acc);
                acc = fmaf(hv.w, whc[4 * k4 + 3], acc);
            }
            accv[r] = acc;
        }
        float zg[R] = {};
        if (w == 1) {
            #pragma unroll
            for (int r = 0; r < R; r++) rg_lds[r][j] = fsig(gxv[r] + accv[r]);
        } else if (w == 0) {
            #pragma unroll
            for (int r = 0; r < R; r++) zg[r] = fsig(gxv[r] + accv[r]);
        }
        __syncthreads();
        if (w == 2) {
            #pragma unroll
            for (int r = 0; r < R; r++)
                hh_lds[r][j] = ftanh(gxv[r] + rg_lds[r][j] * accv[r]);
        }
        __syncthreads();
        if (w == 0) {
            #pragma unroll
            for (int r = 0; r < R; r++) {
                const float hold = h_lds[r][j];
                float hnew = hold;
                if (idv[r] != 0) {
                    const float hh = hh_lds[r][j];
                    hnew = zg[r] * hold + (1.f - zg[r]) * hh;
                }
                h_lds[r][j] = hnew;
                outb[((size_t)(b0 + r) * TT + t) * 128 + dir * 64 + j] = hnew;
            }
        }
        __syncthreads();
    }
    if (dir == 0 && w == 0) {
        #pragma unroll
        for (int r = 0; r < R; r++) hf_out[(size_t)(b0 + r) * 64 + j] = h_lds[r][j];
    }
}

__global__ __launch_bounds__(256, 3) void attn_fp32_kernel(
    const int* __restrict__ ids,
    const float* __restrict__ outb, const float* __restrict__ hf,
    const float* __restrict__ Wk, const float* __restrict__ bk,
    const float* __restrict__ Wq, const float* __restrict__ bq,
    const float* __restrict__ We, const float* __restrict__ be,
    float* __restrict__ ctx)
{
    __shared__ float epart[2][TT];
    __shared__ float e_lds[TT];
    __shared__ float part[4][128];
    const int b = blockIdx.x;
    const int tid = threadIdx.x;
    const int w = tid >> 6;
    const int lane = tid & 63;
    const int cg = w & 1;
    const int tg = w >> 1;
    const int c = cg * 32 + (lane & 31);
    const int h = lane >> 5;
    float wkc[64];
    #pragma unroll
    for (int kk = 0; kk < 64; kk++) wkc[kk] = Wk[(size_t)(64 * h + kk) * 64 + c];
    float qc = bq[c] + bk[c];
    {
        const float4* hf4 = (const float4*)(hf + (size_t)b * 64);
        #pragma unroll
        for (int k4 = 0; k4 < 16; k4++) {
            const float4 hv = hf4[k4];
            qc = fmaf(hv.x, Wq[(4 * k4 + 0) * 64 + c], qc);
            qc = fmaf(hv.y, Wq[(4 * k4 + 1) * 64 + c], qc);
            qc = fmaf(hv.z, Wq[(4 * k4 + 2) * 64 + c], qc);
            qc = fmaf(hv.w, Wq[(4 * k4 + 3) * 64 + c], qc);
        }
    }
    const float wec = We[c];
    const float bev = be[0];
    for (int t = tg; t < TT; t += 2) {
        const float4* o4 = (const float4*)(outb + ((size_t)b * TT + t) * 128 + 64 * h);
        float a0 = 0.f, a1 = 0.f;
        #pragma unroll
        for (int i4 = 0; i4 < 16; i4++) {
            const float4 ov = o4[i4];
            a0 = fmaf(ov.x, wkc[4 * i4 + 0], a0);
            a1 = fmaf(ov.y, wkc[4 * i4 + 1], a1);
            a0 = fmaf(ov.z, wkc[4 * i4 + 2], a0);
            a1 = fmaf(ov.w, wkc[4 * i4 + 3], a1);
        }
        float key = a0 + a1;
        key += __shfl_xor(key, 32);
        float v = ftanh(key + qc) * wec;
        #pragma unroll
        for (int off = 16; off > 0; off >>= 1) v += __shfl_xor(v, off);
        if (lane == 0) epart[cg][t] = v;
    }
    __syncthreads();
    if (w == 0) {
        for (int t = lane; t < TT; t += 64) {
            float e = epart[0][t] + epart[1][t] + bev;
            if (ids[(size_t)b * TT + t] == 0) e -= 1e9f;
            e_lds[t] = e;
        }
        float m = -1e30f;
        for (int t = lane; t < TT; t += 64) m = fmaxf(m, e_lds[t]);
        #pragma unroll
        for (int off = 32; off > 0; off >>= 1) m = fmaxf(m, __shfl_xor(m, off));
        float ssum = 0.f;
        for (int t = lane; t < TT; t += 64) { const float v = __expf(e_lds[t] - m); e_lds[t] = v; ssum += v; }
        #pragma unroll
        for (int off = 32; off > 0; off >>= 1) ssum += __shfl_xor(ssum, off);
        const float inv = 1.f / ssum;
        for (int t = lane; t < TT; t += 64) e_lds[t] *= inv;
    }
    __syncthreads();
    float c0 = 0.f, c1 = 0.f;
    for (int t = w; t < TT; t += 4) {
        const float* orow = outb + ((size_t)b * TT + t) * 128;
        const float wt = e_lds[t];
        c0 = fmaf(wt, orow[lane], c0);
        c1 = fmaf(wt, orow[64 + lane], c1);
    }
    part[w][lane] = c0;
    part[w][64 + lane] = c1;
    __syncthreads();
    if (tid < 128)
        ctx[(size_t)b * 128 + tid] = part[0][tid] + part[1][tid] + part[2][tid] + part[3][tid];
}

extern "C" void kernel_launch(void* const* d_in, const int* in_sizes, int n_in,
                              void* d_out, int out_size, void* d_ws, size_t ws_size,
                              hipStream_t stream) {
    const int*   ids  = (const int*)d_in[0];
    const float* emb  = (const float*)d_in[1];
    const float* Wx_f = (const float*)d_in[2];
    const float* Wh_f = (const float*)d_in[3];
    const float* bi_f = (const float*)d_in[4];
    const float* br_f = (const float*)d_in[5];
    const float* Wx_b = (const float*)d_in[6];
    const float* Wh_b = (const float*)d_in[7];
    const float* bi_b = (const float*)d_in[8];
    const float* br_b = (const float*)d_in[9];
    const float* Wk   = (const float*)d_in[10];
    const float* bk   = (const float*)d_in[11];
    const float* Wq   = (const float*)d_in[12];
    const float* bq   = (const float*)d_in[13];
    const float* We   = (const float*)d_in[14];
    const float* be   = (const float*)d_in[15];
    float* ctx = (float*)d_out;

    const size_t embw_elems = (size_t)VV * 192;          // per-direction elements
    const size_t out_elems  = (size_t)BB * TT * 128;
    const size_t hf_elems   = (size_t)BB * 64;
    const size_t need = embw_elems * 2 * sizeof(float)
                      + out_elems * sizeof(_Float16)
                      + hf_elems * sizeof(float);

    if (ws_size >= need) {
        float* embW_f    = (float*)d_ws;
        float* embW_b    = embW_f + embw_elems;
        _Float16* outb16 = (_Float16*)(embW_b + embw_elems);
        float* hf = (float*)(outb16 + out_elems);
        embw_kernel<<<dim3(VV / 32, 2), 256, 0, stream>>>(
            emb, Wx_f, bi_f, br_f, Wx_b, bi_b, br_b, embW_f, embW_b);
        gru17_kernel<<<dim3(BB / 4, 2), 256, 0, stream>>>(
            ids, embW_f, embW_b, Wh_f, br_f, Wh_b, br_b, outb16, hf);
        attn9_kernel<<<BB, 256, 0, stream>>>(ids, outb16, hf, Wk, bk, Wq, bq, We, be, ctx);
    } else {
        float* outb = (float*)d_ws;
        float* hf   = outb + out_elems;
        gru_kernel<false><<<dim3(BB / 4, 2), 192, 0, stream>>>(
            ids, nullptr, nullptr, emb, Wx_f, bi_f, Wx_b, bi_b,
            Wh_f, br_f, Wh_b, br_b, outb, hf);
        attn_fp32_kernel<<<BB, 256, 0, stream>>>(ids, outb, hf, Wk, bk, Wq, bq, We, be, ctx);
    }
}

// Round 22
// 286.455 us; speedup vs baseline: 1.3063x; 1.3063x over previous
//
#include <hip/hip_runtime.h>
#include <hip/hip_bf16.h>

#define VV 100000
#define EE 50
#define HH 64
#define BB 1024
#define TT 200
// 3H = 192

typedef float v4f __attribute__((ext_vector_type(4)));
typedef float f32x4 __attribute__((ext_vector_type(4)));
typedef _Float16 f16x8 __attribute__((ext_vector_type(8)));
typedef _Float16 f16x2 __attribute__((ext_vector_type(2)));

__device__ __forceinline__ float fsig(float x) {
    return 1.f / (1.f + __expf(-x));
}
__device__ __forceinline__ float ftanh(float x) {
    float e = __expf(2.f * x);
    return 1.f - 2.f / (e + 1.f);
}

// ---------------- Kernel A: embW[v] = emb[v]@Wx + bi (+br for z,r); row-0 pad-mask folded ----
__global__ __launch_bounds__(256) void embw_kernel(
    const float* __restrict__ emb,
    const float* __restrict__ Wx_f, const float* __restrict__ bi_f, const float* __restrict__ br_f,
    const float* __restrict__ Wx_b, const float* __restrict__ bi_b, const float* __restrict__ br_b,
    float* __restrict__ embW_f, float* __restrict__ embW_b)
{
    const float* Wx = blockIdx.y ? Wx_b : Wx_f;
    const float* bi = blockIdx.y ? bi_b : bi_f;
    const float* br = blockIdx.y ? br_b : br_f;
    float* embW     = blockIdx.y ? embW_b : embW_f;
    __shared__ float wx_lds[EE * 192];
    __shared__ float emb_lds[32 * EE];
    const int tid = threadIdx.x;
    const int v0 = blockIdx.x * 32;
    for (int i = tid; i < EE * 192; i += 256) wx_lds[i] = Wx[i];
    for (int i = tid; i < 32 * EE; i += 256) emb_lds[i] = emb[(size_t)v0 * EE + i];
    __syncthreads();
    const int cg = tid & 63;
    const int rg = tid >> 6;
    float acc[8][3];
    #pragma unroll
    for (int i = 0; i < 8; i++) {
        acc[i][0] = bi[cg] + br[cg];              // z: fold br
        acc[i][1] = bi[cg + 64] + br[cg + 64];    // r: fold br
        acc[i][2] = bi[cg + 128];                 // n: br_n stays in the step
    }
    for (int k = 0; k < EE; k++) {
        const float wx0 = wx_lds[k * 192 + cg];
        const float wx1 = wx_lds[k * 192 + cg + 64];
        const float wx2 = wx_lds[k * 192 + cg + 128];
        #pragma unroll
        for (int i = 0; i < 8; i++) {
            const float ev = emb_lds[(rg * 8 + i) * EE + k];
            acc[i][0] = fmaf(ev, wx0, acc[i][0]);
            acc[i][1] = fmaf(ev, wx1, acc[i][1]);
            acc[i][2] = fmaf(ev, wx2, acc[i][2]);
        }
    }
    #pragma unroll
    for (int i = 0; i < 8; i++) {
        const int vrow = v0 + rg * 8 + i;
        const size_t row = (size_t)vrow * 192;
        const bool pad = (vrow == 0);
        embW[row + cg]       = pad ? 38.f : acc[i][0];
        embW[row + cg + 64]  = pad ? 0.f  : acc[i][1];
        embW[row + cg + 128] = pad ? 0.f  : acc[i][2];
    }
}

// ---------------- Kernel B: MFMA GRU, 4-bank zero-move prefetch (gru14; session-best 163us) ----
// 16 seqs/block, 4 waves, 6 MFMA/step. Banks A..D each consumed then reloaded for s+4 (SSA,
// no register shifts -> ~3 steps of gather slack). idsT transposed (conflict-free); stride-88
// hlds; folded mask/bias; f16 outb stores (fire-and-forget).
// Ceiling note: wall = 200 steps x ~1965cyc serial chain (barrier + LDS turnaround + MFMA
// latency + trans-gate chain). Co-residency cannot shorten a serial chain (R21); all
// restructures bracket 163-353us with this the floor.
__global__ __launch_bounds__(256, 1) void gru14_kernel(
    const int* __restrict__ ids,
    const float* __restrict__ eW_f, const float* __restrict__ eW_b,
    const float* __restrict__ Wh_f, const float* __restrict__ br_f,
    const float* __restrict__ Wh_b, const float* __restrict__ br_b,
    _Float16* __restrict__ outb,  // [B, T, 128] f16
    float* __restrict__ hf_out)   // [B, 64] fp32
{
    const int tid  = threadIdx.x;
    const int w    = tid >> 6;
    const int lane = tid & 63;
    const int l15  = lane & 15;
    const int lhi  = lane >> 4;
    const int dir  = blockIdx.y;
    const int b0   = blockIdx.x * 16;
    const float* eW = dir ? eW_b : eW_f;
    const float* Wh = dir ? Wh_b : Wh_f;
    const float* br = dir ? br_b : br_f;
    const int c  = 16 * w + l15;   // hidden column 0..63 owned by this lane
    const int r0 = 4 * lhi;        // this lane's first seq row

    // B-fragments: gate g (0=z,1=r,2=n), k-tile kt; k = 32*kt + 8*lhi + jj, col = 64*g + c.
    f16x8 bw[3][2];
    #pragma unroll
    for (int g = 0; g < 3; g++) {
        #pragma unroll
        for (int kt = 0; kt < 2; kt++) {
            #pragma unroll
            for (int jj = 0; jj < 8; jj++)
                bw[g][kt][jj] = (_Float16)Wh[(size_t)(32 * kt + 8 * lhi + jj) * 192 + 64 * g + c];
        }
    }
    const float brn = br[128 + c];

    __shared__ __align__(16) _Float16 hlds[2][16][88];  // stride 176B
    __shared__ int idsT[TT * 16];                       // transposed [t][seq]
    for (int i = tid; i < TT * 16; i += 256)
        idsT[i] = ids[(size_t)(b0 + (i & 15)) * TT + (i >> 4)];
    for (int i = tid; i < 2 * 16 * 88; i += 256) ((_Float16*)hlds)[i] = (_Float16)0.f;
    float hold[4] = {0.f, 0.f, 0.f, 0.f};   // h[r0+r][c], fp32 master copy
    __syncthreads();

    const int t0 = dir ? (TT - 1) : 0;
    const int dt = dir ? -1 : 1;

    float gxA[3][4], gxB[3][4], gxC[3][4], gxD[3][4];

#define PREF(BANK, SF) { \
    const int tf_ = t0 + (SF) * dt; \
    _Pragma("unroll") \
    for (int r = 0; r < 4; r++) { \
        const int idq_ = idsT[tf_ * 16 + r0 + r]; \
        const float* p_ = eW + (size_t)idq_ * 192 + c; \
        BANK[0][r] = p_[0]; BANK[1][r] = p_[64]; BANK[2][r] = p_[128]; \
    } }

#define STEP(BANK, SCUR) { \
    const int t_ = t0 + (SCUR) * dt; \
    const int nxt_ = cur ^ 1; \
    const f16x8 a0_ = *(const f16x8*)&hlds[cur][l15][8 * lhi]; \
    const f16x8 a1_ = *(const f16x8*)&hlds[cur][l15][32 + 8 * lhi]; \
    f32x4 az0 = {0.f,0.f,0.f,0.f}, ar0 = {0.f,0.f,0.f,0.f}, an0 = {0.f,0.f,0.f,0.f}; \
    f32x4 az1 = {0.f,0.f,0.f,0.f}, ar1 = {0.f,0.f,0.f,0.f}, an1 = {0.f,0.f,0.f,0.f}; \
    az0 = __builtin_amdgcn_mfma_f32_16x16x32_f16(a0_, bw[0][0], az0, 0, 0, 0); \
    ar0 = __builtin_amdgcn_mfma_f32_16x16x32_f16(a0_, bw[1][0], ar0, 0, 0, 0); \
    an0 = __builtin_amdgcn_mfma_f32_16x16x32_f16(a0_, bw[2][0], an0, 0, 0, 0); \
    az1 = __builtin_amdgcn_mfma_f32_16x16x32_f16(a1_, bw[0][1], az1, 0, 0, 0); \
    ar1 = __builtin_amdgcn_mfma_f32_16x16x32_f16(a1_, bw[1][1], ar1, 0, 0, 0); \
    an1 = __builtin_amdgcn_mfma_f32_16x16x32_f16(a1_, bw[2][1], an1, 0, 0, 0); \
    _Pragma("unroll") \
    for (int r = 0; r < 4; r++) { \
        const float z_  = fsig(BANK[0][r] + (az0[r] + az1[r])); \
        const float rg_ = fsig(BANK[1][r] + (ar0[r] + ar1[r])); \
        const float hh_ = ftanh(BANK[2][r] + rg_ * (an0[r] + an1[r] + brn)); \
        const float hn_ = hh_ + z_ * (hold[r] - hh_); \
        hold[r] = hn_; \
        hlds[nxt_][r0 + r][c] = (_Float16)hn_; \
        outb[((size_t)(b0 + r0 + r) * TT + t_) * 128 + dir * 64 + c] = (_Float16)hn_; \
    } \
    cur = nxt_; \
    if ((SCUR) + 4 < TT) PREF(BANK, (SCUR) + 4) \
    asm volatile("s_waitcnt lgkmcnt(0)\n\ts_barrier" ::: "memory"); \
    __builtin_amdgcn_sched_barrier(0); }

    PREF(gxA, 0)
    PREF(gxB, 1)
    PREF(gxC, 2)
    PREF(gxD, 3)
    int cur = 0;
    for (int s = 0; s < TT; s += 4) {
        STEP(gxA, s)
        STEP(gxB, s + 1)
        STEP(gxC, s + 2)
        STEP(gxD, s + 3)
    }
#undef PREF
#undef STEP
    if (dir == 0) {
        #pragma unroll
        for (int r = 0; r < 4; r++)
            hf_out[(size_t)(b0 + r0 + r) * 64 + c] = hold[r];
    }
}

// ---------------- Kernel C: MFMA keys GEMM on f16 outb; f16x2 vectorized context (attn9) ----
#define NTILE 13   // ceil(200/16)

__global__ __launch_bounds__(256) void attn9_kernel(
    const int* __restrict__ ids,
    const _Float16* __restrict__ outb,   // [B,T,128] f16
    const float* __restrict__ hf,        // [B,64] fp32
    const float* __restrict__ Wk, const float* __restrict__ bk,
    const float* __restrict__ Wq, const float* __restrict__ bq,
    const float* __restrict__ We, const float* __restrict__ be,
    float* __restrict__ ctx)             // [B,128]
{
    __shared__ __align__(16) _Float16 wk_sw[1024 * 8];
    __shared__ float q_lds[64];
    __shared__ float we_lds[64];
    __shared__ float e_lds[TT];
    __shared__ float part[4][128];
    const int b = blockIdx.x;
    const int tid = threadIdx.x;
    const int w = tid >> 6;
    const int lane = tid & 63;
    const int l15 = lane & 15;
    const int lhi = lane >> 4;

    #pragma unroll
    for (int i = 0; i < 4; i++) {
        const int slot = tid + 256 * i;
        const int s_l15 = slot & 15;
        const int s_nt  = (slot >> 4) & 3;
        const int s_lhi = (slot >> 6) & 3;
        const int s_ks  = slot >> 8;
        const int kbase = 32 * s_ks + 8 * s_lhi;
        const int col   = 16 * s_nt + s_l15;
        f16x8 v;
        #pragma unroll
        for (int jj = 0; jj < 8; jj++) v[jj] = (_Float16)Wk[(size_t)(kbase + jj) * 64 + col];
        *(f16x8*)&wk_sw[slot * 8] = v;
    }
    if (tid < 64) {
        float qc = bq[tid];
        const float* hfb = hf + (size_t)b * 64;
        for (int k = 0; k < 64; k++) qc = fmaf(hfb[k], Wq[k * 64 + tid], qc);
        q_lds[tid] = qc;
        we_lds[tid] = We[tid];
    }
    __syncthreads();

    for (int tile = w; tile < NTILE; tile += 4) {
        const int t0 = tile * 16;
        const int t = t0 + l15;
        f32x4 acc[4];
        #pragma unroll
        for (int nt = 0; nt < 4; nt++) { acc[nt][0] = 0.f; acc[nt][1] = 0.f; acc[nt][2] = 0.f; acc[nt][3] = 0.f; }
        #pragma unroll
        for (int ks = 0; ks < 4; ks++) {
            f16x8 a;
            if (t < TT) {
                a = *(const f16x8*)(outb + ((size_t)b * TT + t) * 128 + 32 * ks + 8 * lhi);
            } else {
                #pragma unroll
                for (int jj = 0; jj < 8; jj++) a[jj] = (_Float16)0.f;
            }
            #pragma unroll
            for (int nt = 0; nt < 4; nt++) {
                const f16x8 bf = *(const f16x8*)&wk_sw[(ks * 256 + lhi * 64 + nt * 16 + l15) * 8];
                acc[nt] = __builtin_amdgcn_mfma_f32_16x16x32_f16(a, bf, acc[nt], 0, 0, 0);
            }
        }
        float ep0 = 0.f, ep1 = 0.f, ep2 = 0.f, ep3 = 0.f;
        #pragma unroll
        for (int nt = 0; nt < 4; nt++) {
            const int c = 16 * nt + l15;
            const float qn = q_lds[c];
            const float wen = we_lds[c];
            ep0 = fmaf(wen, ftanh(acc[nt][0] + qn), ep0);
            ep1 = fmaf(wen, ftanh(acc[nt][1] + qn), ep1);
            ep2 = fmaf(wen, ftanh(acc[nt][2] + qn), ep2);
            ep3 = fmaf(wen, ftanh(acc[nt][3] + qn), ep3);
        }
        #pragma unroll
        for (int off = 1; off < 16; off <<= 1) {
            ep0 += __shfl_xor(ep0, off);
            ep1 += __shfl_xor(ep1, off);
            ep2 += __shfl_xor(ep2, off);
            ep3 += __shfl_xor(ep3, off);
        }
        if (l15 == 0) {
            const int rbase = t0 + 4 * lhi;
            if (rbase + 0 < TT) e_lds[rbase + 0] = ep0;
            if (rbase + 1 < TT) e_lds[rbase + 1] = ep1;
            if (rbase + 2 < TT) e_lds[rbase + 2] = ep2;
            if (rbase + 3 < TT) e_lds[rbase + 3] = ep3;
        }
    }
    __syncthreads();
    if (w == 0) {
        const float bev = be[0];
        for (int t = lane; t < TT; t += 64) {
            float e = e_lds[t] + bev;
            if (ids[(size_t)b * TT + t] == 0) e -= 1e9f;
            e_lds[t] = e;
        }
        float m = -1e30f;
        for (int t = lane; t < TT; t += 64) m = fmaxf(m, e_lds[t]);
        #pragma unroll
        for (int off = 32; off > 0; off >>= 1) m = fmaxf(m, __shfl_xor(m, off));
        float ssum = 0.f;
        for (int t = lane; t < TT; t += 64) { const float v = __expf(e_lds[t] - m); e_lds[t] = v; ssum += v; }
        #pragma unroll
        for (int off = 32; off > 0; off >>= 1) ssum += __shfl_xor(ssum, off);
        const float inv = 1.f / ssum;
        for (int t = lane; t < TT; t += 64) e_lds[t] *= inv;
    }
    __syncthreads();
    float c0 = 0.f, c1 = 0.f;
    for (int t = w; t < TT; t += 4) {
        const f16x2 hv = *(const f16x2*)(outb + ((size_t)b * TT + t) * 128 + 2 * lane);
        const float wt = e_lds[t];
        c0 = fmaf(wt, (float)hv[0], c0);
        c1 = fmaf(wt, (float)hv[1], c1);
    }
    part[w][2 * lane]     = c0;
    part[w][2 * lane + 1] = c1;
    __syncthreads();
    if (tid < 128)
        ctx[(size_t)b * 128 + tid] = part[0][tid] + part[1][tid] + part[2][tid] + part[3][tid];
}

// ---------------- (fallback, fp32 end-to-end) ----------------
template<bool USE_EMBW>
__global__ __launch_bounds__(192, 2) void gru_kernel(
    const int* __restrict__ ids,
    const float* __restrict__ embW_f, const float* __restrict__ embW_b,
    const float* __restrict__ emb,
    const float* __restrict__ Wx_f, const float* __restrict__ bi_f,
    const float* __restrict__ Wx_b, const float* __restrict__ bi_b,
    const float* __restrict__ Wh_f, const float* __restrict__ br_f,
    const float* __restrict__ Wh_b, const float* __restrict__ br_b,
    float* __restrict__ outb, float* __restrict__ hf_out)
{
    constexpr int R = 4;
    __shared__ float h_lds[R][64];
    __shared__ float rg_lds[R][64];
    __shared__ float hh_lds[R][64];
    __shared__ int ids_lds[R * TT];
    const int tid = threadIdx.x;
    const int w = tid >> 6;
    const int j = tid & 63;
    const int dir = blockIdx.y;
    const int b0 = blockIdx.x * R;
    const float* Wh   = dir ? Wh_b : Wh_f;
    const float* br   = dir ? br_b : br_f;
    const float* Wx   = dir ? Wx_b : Wx_f;
    const float* bi   = dir ? bi_b : bi_f;
    const int c = w * 64 + j;

    float whc[64];
    #pragma unroll
    for (int k = 0; k < 64; k++) whc[k] = Wh[k * 192 + c];
    const float brc = br[c];
    float wxc[EE];
    float bic = 0.f;
    if (!USE_EMBW) {
        #pragma unroll
        for (int k = 0; k < EE; k++) wxc[k] = Wx[k * 192 + c];
        bic = bi[c];
    }
    for (int i = tid; i < R * TT; i += 192) ids_lds[i] = ids[(size_t)b0 * TT + i];
    if (w == 0) {
        #pragma unroll
        for (int r = 0; r < R; r++) h_lds[r][j] = 0.f;
    }
    __syncthreads();

    for (int s = 0; s < TT; s++) {
        const int t = dir ? (TT - 1 - s) : s;
        int idv[R];
        float gxv[R], accv[R];
        #pragma unroll
        for (int r = 0; r < R; r++) idv[r] = ids_lds[r * TT + t];
        #pragma unroll
        for (int r = 0; r < R; r++) {
            float acc = bic;
            const float* er = emb + (size_t)idv[r] * EE;
            #pragma unroll
            for (int k = 0; k < EE; k++) acc = fmaf(er[k], wxc[k], acc);
            gxv[r] = acc;
        }
        #pragma unroll
        for (int r = 0; r < R; r++) {
            float acc = brc;
            const float4* h4 = (const float4*)(&h_lds[r][0]);
            #pragma unroll
            for (int k4 = 0; k4 < 16; k4++) {
                const float4 hv = h4[k4];
                acc = fmaf(hv.x, whc[4 * k4 + 0], acc);
                acc = fmaf(hv.y, whc[4 * k4 + 1], acc);
                acc = fmaf(hv.z, whc[4 * k4 + 2], acc);
                acc = fmaf(hv.w, whc[4 * k4 + 3], acc);
            }
            accv[r] = acc;
        }
        float zg[R] = {};
        if (w == 1) {
            #pragma unroll
            for (int r = 0; r < R; r++) rg_lds[r][j] = fsig(gxv[r] + accv[r]);
        } else if (w == 0) {
            #pragma unroll
            for (int r = 0; r < R; r++) zg[r] = fsig(gxv[r] + accv[r]);
        }
        __syncthreads();
        if (w == 2) {
            #pragma unroll
            for (int r = 0; r < R; r++)
                hh_lds[r][j] = ftanh(gxv[r] + rg_lds[r][j] * accv[r]);
        }
        __syncthreads();
        if (w == 0) {
            #pragma unroll
            for (int r = 0; r < R; r++) {
                const float hold = h_lds[r][j];
                float hnew = hold;
                if (idv[r] != 0) {
                    const float hh = hh_lds[r][j];
                    hnew = zg[r] * hold + (1.f - zg[r]) * hh;
                }
                h_lds[r][j] = hnew;
                outb[((size_t)(b0 + r) * TT + t) * 128 + dir * 64 + j] = hnew;
            }
        }
        __syncthreads();
    }
    if (dir == 0 && w == 0) {
        #pragma unroll
        for (int r = 0; r < R; r++) hf_out[(size_t)(b0 + r) * 64 + j] = h_lds[r][j];
    }
}

__global__ __launch_bounds__(256, 3) void attn_fp32_kernel(
    const int* __restrict__ ids,
    const float* __restrict__ outb, const float* __restrict__ hf,
    const float* __restrict__ Wk, const float* __restrict__ bk,
    const float* __restrict__ Wq, const float* __restrict__ bq,
    const float* __restrict__ We, const float* __restrict__ be,
    float* __restrict__ ctx)
{
    __shared__ float epart[2][TT];
    __shared__ float e_lds[TT];
    __shared__ float part[4][128];
    const int b = blockIdx.x;
    const int tid = threadIdx.x;
    const int w = tid >> 6;
    const int lane = tid & 63;
    const int cg = w & 1;
    const int tg = w >> 1;
    const int c = cg * 32 + (lane & 31);
    const int h = lane >> 5;
    float wkc[64];
    #pragma unroll
    for (int kk = 0; kk < 64; kk++) wkc[kk] = Wk[(size_t)(64 * h + kk) * 64 + c];
    float qc = bq[c] + bk[c];
    {
        const float4* hf4 = (const float4*)(hf + (size_t)b * 64);
        #pragma unroll
        for (int k4 = 0; k4 < 16; k4++) {
            const float4 hv = hf4[k4];
            qc = fmaf(hv.x, Wq[(4 * k4 + 0) * 64 + c], qc);
            qc = fmaf(hv.y, Wq[(4 * k4 + 1) * 64 + c], qc);
            qc = fmaf(hv.z, Wq[(4 * k4 + 2) * 64 + c], qc);
            qc = fmaf(hv.w, Wq[(4 * k4 + 3) * 64 + c], qc);
        }
    }
    const float wec = We[c];
    const float bev = be[0];
    for (int t = tg; t < TT; t += 2) {
        const float4* o4 = (const float4*)(outb + ((size_t)b * TT + t) * 128 + 64 * h);
        float a0 = 0.f, a1 = 0.f;
        #pragma unroll
        for (int i4 = 0; i4 < 16; i4++) {
            const float4 ov = o4[i4];
            a0 = fmaf(ov.x, wkc[4 * i4 + 0], a0);
            a1 = fmaf(ov.y, wkc[4 * i4 + 1], a1);
            a0 = fmaf(ov.z, wkc[4 * i4 + 2], a0);
            a1 = fmaf(ov.w, wkc[4 * i4 + 3], a1);
        }
        float key = a0 + a1;
        key += __shfl_xor(key, 32);
        float v = ftanh(key + qc) * wec;
        #pragma unroll
        for (int off = 16; off > 0; off >>= 1) v += __shfl_xor(v, off);
        if (lane == 0) epart[cg][t] = v;
    }
    __syncthreads();
    if (w == 0) {
        for (int t = lane; t < TT; t += 64) {
            float e = epart[0][t] + epart[1][t] + bev;
            if (ids[(size_t)b * TT + t] == 0) e -= 1e9f;
            e_lds[t] = e;
        }
        float m = -1e30f;
        for (int t = lane; t < TT; t += 64) m = fmaxf(m, e_lds[t]);
        #pragma unroll
        for (int off = 32; off > 0; off >>= 1) m = fmaxf(m, __shfl_xor(m, off));
        float ssum = 0.f;
        for (int t = lane; t < TT; t += 64) { const float v = __expf(e_lds[t] - m); e_lds[t] = v; ssum += v; }
        #pragma unroll
        for (int off = 32; off > 0; off >>= 1) ssum += __shfl_xor(ssum, off);
        const float inv = 1.f / ssum;
        for (int t = lane; t < TT; t += 64) e_lds[t] *= inv;
    }
    __syncthreads();
    float c0 = 0.f, c1 = 0.f;
    for (int t = w; t < TT; t += 4) {
        const float* orow = outb + ((size_t)b * TT + t) * 128;
        const float wt = e_lds[t];
        c0 = fmaf(wt, orow[lane], c0);
        c1 = fmaf(wt, orow[64 + lane], c1);
    }
    part[w][lane] = c0;
    part[w][64 + lane] = c1;
    __syncthreads();
    if (tid < 128)
        ctx[(size_t)b * 128 + tid] = part[0][tid] + part[1][tid] + part[2][tid] + part[3][tid];
}

extern "C" void kernel_launch(void* const* d_in, const int* in_sizes, int n_in,
                              void* d_out, int out_size, void* d_ws, size_t ws_size,
                              hipStream_t stream) {
    const int*   ids  = (const int*)d_in[0];
    const float* emb  = (const float*)d_in[1];
    const float* Wx_f = (const float*)d_in[2];
    const float* Wh_f = (const float*)d_in[3];
    const float* bi_f = (const float*)d_in[4];
    const float* br_f = (const float*)d_in[5];
    const float* Wx_b = (const float*)d_in[6];
    const float* Wh_b = (const float*)d_in[7];
    const float* bi_b = (const float*)d_in[8];
    const float* br_b = (const float*)d_in[9];
    const float* Wk   = (const float*)d_in[10];
    const float* bk   = (const float*)d_in[11];
    const float* Wq   = (const float*)d_in[12];
    const float* bq   = (const float*)d_in[13];
    const float* We   = (const float*)d_in[14];
    const float* be   = (const float*)d_in[15];
    float* ctx = (float*)d_out;

    const size_t embw_elems = (size_t)VV * 192;          // per-direction elements
    const size_t out_elems  = (size_t)BB * TT * 128;
    const size_t hf_elems   = (size_t)BB * 64;
    const size_t need = embw_elems * 2 * sizeof(float)
                      + out_elems * sizeof(_Float16)
                      + hf_elems * sizeof(float);

    if (ws_size >= need) {
        float* embW_f    = (float*)d_ws;
        float* embW_b    = embW_f + embw_elems;
        _Float16* outb16 = (_Float16*)(embW_b + embw_elems);
        float* hf = (float*)(outb16 + out_elems);
        embw_kernel<<<dim3(VV / 32, 2), 256, 0, stream>>>(
            emb, Wx_f, bi_f, br_f, Wx_b, bi_b, br_b, embW_f, embW_b);
        gru14_kernel<<<dim3(BB / 16, 2), 256, 0, stream>>>(
            ids, embW_f, embW_b, Wh_f, br_f, Wh_b, br_b, outb16, hf);
        attn9_kernel<<<BB, 256, 0, stream>>>(ids, outb16, hf, Wk, bk, Wq, bq, We, be, ctx);
    } else {
        float* outb = (float*)d_ws;
        float* hf   = outb + out_elems;
        gru_kernel<false><<<dim3(BB / 4, 2), 192, 0, stream>>>(
            ids, nullptr, nullptr, emb, Wx_f, bi_f, Wx_b, bi_b,
            Wh_f, br_f, Wh_b, br_b, outb, hf);
        attn_fp32_kernel<<<BB, 256, 0, stream>>>(ids, outb, hf, Wk, bk, Wq, bq, We, be, ctx);
    }
}